// Round 12
// baseline (312.003 us; speedup 1.0000x reference)
//
#include <hip/hip_runtime.h>
#include <math.h>

// VIN forward on MI355X — single fused kernel, 128 WGs x 1024 thr (16 waves).
// Sizes: N=128, H=W=64, CH_I=2, CH_H=150, CH_Q=10, N_ACT=8, VInum=36.
//
// R21 -> R22 (single change vs R19-best: weight load PATH, not residency):
//  Residency is dead (R18/R20/R21: SGPRs don't fit architecturally, VGPR
//  allocator hard-caps at 128 here, asm pins don't protect array lifetimes).
//  Invariant across the 102-109us plateau: ~45 wave-uniform weight s_loads
//  per iter through the shared scalar pipe/K$. With ~10 free SGPRs the
//  compiler reloads in ~5-pair batches -> ~9x (s_load -> lgkmcnt(0) -> use)
//  serialization points per iter, each draining the DS queue too (SMEM is
//  out-of-order); 16 waves hit the shared SQC simultaneously post-barrier
//  (720 SMEM/CU/iter) so TLP can't hide it. R19's FETCH tripling (weights
//  re-fetched per iter) corroborates. Fix: pin the weight base pointer into
//  a VGPR (asm "+v", re-pinned per iter to defeat LICM) -> compiler must
//  emit global_load_dwordx2: per-CU L1 (360B hot, no SQC contention),
//  vmcnt-precise waits decoupled from lgkmcnt, latency covered by 4-wave
//  TLP. Identical floats, identical d=0..8 chain order -> bit-identical.

typedef float v2f __attribute__((ext_vector_type(2)));

static __device__ __forceinline__ v2f splat2(float s) { v2f r; r.x = s; r.y = s; return r; }
static __device__ __forceinline__ v2f pkfma(v2f w, float v, v2f a) {
#if __has_builtin(__builtin_elementwise_fma)
    return __builtin_elementwise_fma(w, splat2(v), a);
#else
    v2f r; r.x = fmaf(w.x, v, a.x); r.y = fmaf(w.y, v, a.y); return r;
#endif
}
static __device__ __forceinline__ v2f pkmax(v2f a, v2f b) {
#if __has_builtin(__builtin_elementwise_max)
    return __builtin_elementwise_max(a, b);
#else
    v2f r; r.x = fmaxf(a.x, b.x); r.y = fmaxf(a.y, b.y); return r;
#endif
}

// DPP wave-wide shift by one lane. bound-invalid lanes keep old (=0) ->
// zero halo at lanes 0/63.
#define DPP_SHR1 0x138   // lane n <- lane n-1  (left-neighbor value)
#define DPP_SHL1 0x130   // lane n <- lane n+1  (right-neighbor value)
template <int CTRL>
static __device__ __forceinline__ float dppsh(float v) {
    return __int_as_float(__builtin_amdgcn_update_dpp(
        0, __float_as_int(v), CTRL, 0xF, 0xF, false));
}

#define XROW 69
#define RROW 68                  // rs row stride; idx = (grow+1)*68 + col + 2

__global__ void
__attribute__((amdgpu_flat_work_group_size(1024, 1024)))
__attribute__((amdgpu_waves_per_eu(4, 4)))
vin_kernel(const float* __restrict__ x,
           const int* __restrict__ S1,
           const int* __restrict__ S2,
           const int* __restrict__ VInum,
           const float* __restrict__ w0,
           const float* __restrict__ b0,
           const float* __restrict__ w_r,
           const float* __restrict__ w_q,
           const float* __restrict__ w_sw,
           const float* __restrict__ w_sw2,
           const float* __restrict__ w_dense,
           float* __restrict__ out) {
    const int b = blockIdx.x;
    const int t = threadIdx.x;

    __shared__ float xs0[68 * XROW];     // x ch0, [y+2][x+2], 2-halo of zeros
    __shared__ float xs1[68 * XROW];     // x ch1
    __shared__ float rs[66 * RROW];      // r, pad-2 layout, zero halos
    __shared__ float wtA[1620];          // P chunk partials: 162 entries x 10
    __shared__ float Pp[450];            // P[d][e5x5][ci], zero-init
    __shared__ float Bt[90];             // bias chunk partials
    __shared__ float Bv[9];              // B[d] = w_r[d].b0
    __shared__ float W5c[459];           // 9 classes x (50 weights + bias)
    __shared__ float exT[2][17][64];     // per-wave TOP-row edge, by parity
    __shared__ float exB[2][17][64];     // per-wave BOTTOM-row edge, by parity
    __shared__ float qsel[10];

    // ---- zero LDS (halos/slot-16 must be 0; Pp must be 0) ----
    for (int i = t; i < 68 * XROW; i += 1024) { xs0[i] = 0.f; xs1[i] = 0.f; }
    for (int i = t; i < 66 * RROW; i += 1024) rs[i] = 0.f;
    for (int i = t; i < 2 * 17 * 64; i += 1024) {
        ((float*)exT)[i] = 0.f; ((float*)exB)[i] = 0.f;
    }
    if (t < 450) Pp[t] = 0.f;
    __syncthreads();

    const int row = t >> 4;          // 0..63 (prologue mapping)
    const int cb  = (t & 15) << 2;   // 0,4,...,60

    // ---- stage x (8 contiguous floats = 2x float4 per thread) ----
    {
        const float* xb = x + (size_t)b * 64 * 64 * 2;
        const float4* xp = (const float4*)(xb + (row * 64 + cb) * 2);
        #pragma unroll
        for (int g = 0; g < 2; ++g) {
            float4 v4 = xp[g];
            int px = cb + g * 2;
            xs0[(row + 2) * XROW + px + 2] = v4.x;
            xs1[(row + 2) * XROW + px + 2] = v4.y;
            xs0[(row + 2) * XROW + px + 3] = v4.z;
            xs1[(row + 2) * XROW + px + 3] = v4.w;
        }
    }
    // ---- round A: P chunk partials (1620 items) + bias chunks (90) ----
    for (int idx = t; idx < 1620; idx += 1024) {
        int entry = idx / 10, ch = idx - entry * 10;
        int d = entry / 18, rem = entry % 18;
        int uu = rem >> 1, ci = rem & 1;
        int c0 = ch * 15;
        const float* wr = w_r + d * 150;
        const float* wp = w0 + (uu * 2 + ci) * 150;
        float s = 0.f;
        for (int c = c0; c < c0 + 15; ++c) s += wr[c] * wp[c];
        wtA[idx] = s;
    }
    if (t < 90) {
        int d = t / 10, ch = t - d * 10, c0 = ch * 15;
        float s = 0.f;
        for (int c = c0; c < c0 + 15; ++c) s += w_r[d * 150 + c] * b0[c];
        Bt[t] = s;
    }
    __syncthreads();
    // ---- round B: reduce P entries (162) and B (9) ----
    if (t < 162) {
        float s = 0.f;
        #pragma unroll
        for (int i = 0; i < 10; ++i) s += wtA[t * 10 + i];
        int d = t / 18, rem = t % 18;
        int uu = rem >> 1, ci = rem & 1;
        int dy = d / 3 - 1, dx = d % 3 - 1;
        int uy = uu / 3 - 1, ux = uu % 3 - 1;
        int eidx = (dy + uy + 2) * 5 + (dx + ux + 2);
        Pp[d * 50 + eidx * 2 + ci] = s;
    } else if (t >= 256 && t < 265) {
        int d = t - 256;
        float s = 0.f;
        #pragma unroll
        for (int i = 0; i < 10; ++i) s += Bt[d * 10 + i];
        Bv[d] = s;
    }
    __syncthreads();
    // ---- round C: class subset-sums W5c[9][51] ----
    if (t < 459) {
        int cls = t / 51, j = t - cls * 51;
        int cy = cls / 3, cx = cls % 3;
        float s = 0.f;
        #pragma unroll
        for (int d = 0; d < 9; ++d) {
            int dy = d / 3 - 1, dx = d % 3 - 1;
            bool ok = (cy == 0 || (cy == 1 ? dy >= 0 : dy <= 0)) &&
                      (cx == 0 || (cx == 1 ? dx >= 0 : dx <= 0));
            if (ok) s += (j < 50) ? Pp[d * 50 + j] : Bv[d];
        }
        W5c[t] = s;
    }
    __syncthreads();

    // ---- r everywhere via class-weighted 5x5 stencil (4 px/thread) ----
    {
        int cy = (row == 0) ? 1 : (row == 63) ? 2 : 0;
        #pragma unroll
        for (int p = 0; p < 4; ++p) {
            int xx = cb + p;
            int cx = (xx == 0) ? 1 : (xx == 63) ? 2 : 0;
            const float* Wp = &W5c[(cy * 3 + cx) * 51];
            float acc = Wp[50];
            #pragma unroll
            for (int e = 0; e < 25; ++e) {
                int xi = (row + e / 5) * XROW + (xx + e % 5);
                acc = fmaf(xs0[xi], Wp[e * 2], acc);
                acc = fmaf(xs1[xi], Wp[e * 2 + 1], acc);
            }
            rs[(row + 1) * RROW + xx + 2] = acc;
        }
    }
    __syncthreads();

    // ============ column-per-lane mapping from here on ============
    const int c  = t & 63;           // column 0..63 (lane)
    const int w  = t >> 6;           // wave 0..15, owns rows 4w..4w+3
    const int r0 = w << 2;
    const int upSlot = (w == 0)  ? 16 : w - 1;   // exB[.][upSlot] = row r0-1
    const int dnSlot = (w == 15) ? 16 : w + 1;   // exT[.][dnSlot] = row r0+4
    const int K = VInum[0];

    // ---- Rsw precompute + first step (w_q): r window via DPP ----
    v2f Rsw2[4][5];
    float vprev[4];
    float RC[6], RL[6], RR[6];
    #pragma unroll
    for (int j = 0; j < 6; ++j) RC[j] = rs[(r0 + j) * RROW + c + 2];  // rows r0-1..r0+4
    #pragma unroll
    for (int j = 0; j < 6; ++j) { RL[j] = dppsh<DPP_SHR1>(RC[j]); RR[j] = dppsh<DPP_SHL1>(RC[j]); }
    {
        float vmax[4];
        #pragma unroll
        for (int a = 0; a < 10; ++a) {
            #pragma unroll
            for (int i = 0; i < 4; ++i) {
                float accR = 0.f, accQ = 0.f;
                #pragma unroll
                for (int d = 0; d < 9; ++d) {
                    const int dy = d / 3, dx = d % 3;
                    const float rv = (dx == 0 ? RL : dx == 1 ? RC : RR)[i + dy];
                    accR = fmaf(w_sw[d * 20 + a], rv, accR);
                    accQ = fmaf(w_q[d * 20 + a],  rv, accQ);
                }
                if (a & 1) Rsw2[i][a >> 1].y = accR; else Rsw2[i][a >> 1].x = accR;
                vmax[i] = (a == 0) ? accQ : fmaxf(vmax[i], accQ);
            }
        }
        exT[1][w][c] = vmax[0];          // v^1 edges, parity 1
        exB[1][w][c] = vmax[3];
        #pragma unroll
        for (int i = 0; i < 4; ++i) vprev[i] = vmax[i];
    }
    __syncthreads();

    // ---- weight base pointer forced into a VGPR -> in-loop weight loads
    // become global_load_dwordx2 (VMEM/L1, vmcnt-counted), NOT s_load ----
    const float* wpv = w_sw + 10;        // v-part weights base
    asm volatile("" : "+v"(wpv));

    // ---- K-1 shared-weight VI steps: register v + DPP + edge exchange ----
    for (int k = 2; k <= K; ++k) {
        asm volatile("" : "+v"(wpv));    // re-pin: defeat LICM/CSE across iters
        const int pr = (k - 1) & 1, pw = k & 1;
        float VC[6], VL[6], VR[6];
        VC[0] = exB[pr][upSlot][c];      // row r0-1 (neighbor wave / halo 0)
        VC[5] = exT[pr][dnSlot][c];      // row r0+4
        #pragma unroll
        for (int i = 0; i < 4; ++i) VC[i + 1] = vprev[i];
        #pragma unroll
        for (int j = 0; j < 6; ++j) { VL[j] = dppsh<DPP_SHR1>(VC[j]); VR[j] = dppsh<DPP_SHL1>(VC[j]); }

        v2f acc[4][5];
        #pragma unroll
        for (int ap = 0; ap < 5; ++ap) {
            #pragma unroll
            for (int d = 0; d < 9; ++d) {
                v2f w2 = *(const v2f*)(wpv + d * 20 + 2 * ap);  // VMEM, 8B-aligned
                const int dy = d / 3, dx = d % 3;
                const float* S = (dx == 0) ? VL : (dx == 1) ? VC : VR;
                #pragma unroll
                for (int i = 0; i < 4; ++i)
                    acc[i][ap] = (d == 0) ? pkfma(w2, S[i + dy], Rsw2[i][ap])
                                          : pkfma(w2, S[i + dy], acc[i][ap]);
            }
        }
        float vnew[4];
        #pragma unroll
        for (int i = 0; i < 4; ++i) {
            v2f m2 = acc[i][0];
            #pragma unroll
            for (int ap = 1; ap < 5; ++ap) m2 = pkmax(m2, acc[i][ap]);
            vnew[i] = fmaxf(m2.x, m2.y);
        }
        exT[pw][w][c] = vnew[0];         // publish v^k edges
        exB[pw][w][c] = vnew[3];
        #pragma unroll
        for (int i = 0; i < 4; ++i) vprev[i] = vnew[i];
        __syncthreads();
    }

    // ---- final step with w_sw2: q -> global, gather (S1,S2) ----
    const int s1 = S1[b], s2 = S2[b];
    {
        const int pK = K & 1;
        float VC[6], VL[6], VR[6];
        VC[0] = exB[pK][upSlot][c];
        VC[5] = exT[pK][dnSlot][c];
        #pragma unroll
        for (int i = 0; i < 4; ++i) VC[i + 1] = vprev[i];
        #pragma unroll
        for (int j = 0; j < 6; ++j) { VL[j] = dppsh<DPP_SHR1>(VC[j]); VR[j] = dppsh<DPP_SHL1>(VC[j]); }

        float qv[4][10];
        #pragma unroll
        for (int a = 0; a < 10; ++a) {
            #pragma unroll
            for (int i = 0; i < 4; ++i) {
                float acc = 0.f;
                #pragma unroll
                for (int d = 0; d < 9; ++d) {
                    const int dy = d / 3, dx = d % 3;
                    acc = fmaf(w_sw2[d * 20 + a],
                               (dx == 0 ? RL : dx == 1 ? RC : RR)[i + dy], acc);
                    acc = fmaf(w_sw2[d * 20 + 10 + a],
                               (dx == 0 ? VL : dx == 1 ? VC : VR)[i + dy], acc);
                }
                qv[i][a] = acc;
            }
        }
        // store q: 10 floats per px, 8B-aligned -> 5x float2 per row
        #pragma unroll
        for (int i = 0; i < 4; ++i) {
            float2* qp = (float2*)(out + 2048 +
                          ((size_t)((b * 64 + r0 + i) * 64 + c)) * 10);
            #pragma unroll
            for (int g = 0; g < 5; ++g)
                qp[g] = make_float2(qv[i][2 * g], qv[i][2 * g + 1]);
        }
        if (c == s2) {
            #pragma unroll
            for (int i = 0; i < 4; ++i)
                if (s1 == r0 + i) {
                    #pragma unroll
                    for (int a = 0; a < 10; ++a) qsel[a] = qv[i][a];
                }
        }
    }
    __syncthreads();

    // ---- dense + softmax (thread 0), q_out (threads 0..9) ----
    if (t == 0) {
        float logits[8];
        float m = -1e30f;
        #pragma unroll
        for (int j = 0; j < 8; ++j) {
            float s = 0.f;
            #pragma unroll
            for (int a = 0; a < 10; ++a) s += qsel[a] * w_dense[a * 8 + j];
            logits[j] = s;
            m = fmaxf(m, s);
        }
        float sum = 0.f;
        float e[8];
        #pragma unroll
        for (int j = 0; j < 8; ++j) { e[j] = expf(logits[j] - m); sum += e[j]; }
        float inv = 1.f / sum;
        #pragma unroll
        for (int j = 0; j < 8; ++j) {
            out[b * 8 + j] = logits[j];
            out[1024 + b * 8 + j] = e[j] * inv;
        }
    }
    if (t < 10) out[5244928 + b * 10 + t] = qsel[t];
}

extern "C" void kernel_launch(void* const* d_in, const int* in_sizes, int n_in,
                              void* d_out, int out_size, void* d_ws, size_t ws_size,
                              hipStream_t stream) {
    const float* x      = (const float*)d_in[0];
    const int*   S1     = (const int*)d_in[1];
    const int*   S2     = (const int*)d_in[2];
    const int*   VInum  = (const int*)d_in[3];
    const float* w0     = (const float*)d_in[4];
    const float* b0     = (const float*)d_in[5];
    const float* w_r    = (const float*)d_in[6];
    const float* w_q    = (const float*)d_in[7];
    const float* w_sw   = (const float*)d_in[8];
    const float* w_sw2  = (const float*)d_in[9];
    const float* w_dense= (const float*)d_in[10];
    float* out = (float*)d_out;

    vin_kernel<<<128, 1024, 0, stream>>>(x, S1, S2, VInum, w0, b0, w_r, w_q,
                                         w_sw, w_sw2, w_dense, out);
}

// Round 13
// 229.674 us; speedup vs baseline: 1.3585x; 1.3585x over previous
//
#include <hip/hip_runtime.h>
#include <math.h>

// VIN forward on MI355X — single fused kernel, 128 WGs x 1024 thr (16 waves).
// Sizes: N=128, H=W=64, CH_I=2, CH_H=150, CH_Q=10, N_ACT=8, VInum=36.
//
// R22 -> R23 (single change vs R19-best: weight operand path = LDS broadcast):
//  Operand-path scorecard in the R19 DPP structure: SMEM 102us (baseline,
//  suspect: 45 s_loads/iter + out-of-order lgkmcnt(0) drains that flush the
//  DS queue), VMEM 246us (R22: per-lane loads for uniform data — dead),
//  SGPR impossible (90 > budget), VGPR refused by allocator (cap 128).
//  Last untested cell: LDS. Stage the 45 v-part pairs ONCE into swv2[9][6]
//  (48B row stride -> 16B-aligned), then read in-loop with IN-ORDER,
//  precisely-counted DS reads. Broadcast (all lanes same addr) = conflict-
//  free. Loop restructured d-outer/ap-inner: one d = 5 contiguous pairs =
//  2x ds_read_b128 + 1x ds_read_b64 feeding 20 pkfma (27 reads/iter, was
//  45 s_loads). Per-(i,ap) chain still d=0..8 ascending, identical floats
//  -> bit-identical. All else identical to R19.
//  Pre-committed: null result (+-3us) falsifies the SMEM theory -> R24 =
//  temporal blocking (2 VI steps per barrier).

typedef float v2f __attribute__((ext_vector_type(2)));

static __device__ __forceinline__ v2f splat2(float s) { v2f r; r.x = s; r.y = s; return r; }
static __device__ __forceinline__ v2f pkfma(v2f w, float v, v2f a) {
#if __has_builtin(__builtin_elementwise_fma)
    return __builtin_elementwise_fma(w, splat2(v), a);
#else
    v2f r; r.x = fmaf(w.x, v, a.x); r.y = fmaf(w.y, v, a.y); return r;
#endif
}
static __device__ __forceinline__ v2f pkmax(v2f a, v2f b) {
#if __has_builtin(__builtin_elementwise_max)
    return __builtin_elementwise_max(a, b);
#else
    v2f r; r.x = fmaxf(a.x, b.x); r.y = fmaxf(a.y, b.y); return r;
#endif
}

// DPP wave-wide shift by one lane. bound-invalid lanes keep old (=0) ->
// zero halo at lanes 0/63.
#define DPP_SHR1 0x138   // lane n <- lane n-1  (left-neighbor value)
#define DPP_SHL1 0x130   // lane n <- lane n+1  (right-neighbor value)
template <int CTRL>
static __device__ __forceinline__ float dppsh(float v) {
    return __int_as_float(__builtin_amdgcn_update_dpp(
        0, __float_as_int(v), CTRL, 0xF, 0xF, false));
}

#define XROW 69
#define RROW 68                  // rs row stride; idx = (grow+1)*68 + col + 2

__global__ void
__attribute__((amdgpu_flat_work_group_size(1024, 1024)))
__attribute__((amdgpu_waves_per_eu(4, 4)))
vin_kernel(const float* __restrict__ x,
           const int* __restrict__ S1,
           const int* __restrict__ S2,
           const int* __restrict__ VInum,
           const float* __restrict__ w0,
           const float* __restrict__ b0,
           const float* __restrict__ w_r,
           const float* __restrict__ w_q,
           const float* __restrict__ w_sw,
           const float* __restrict__ w_sw2,
           const float* __restrict__ w_dense,
           float* __restrict__ out) {
    const int b = blockIdx.x;
    const int t = threadIdx.x;

    __shared__ float xs0[68 * XROW];     // x ch0, [y+2][x+2], 2-halo of zeros
    __shared__ float xs1[68 * XROW];     // x ch1
    __shared__ float rs[66 * RROW];      // r, pad-2 layout, zero halos
    __shared__ float wtA[1620];          // P chunk partials: 162 entries x 10
    __shared__ float Pp[450];            // P[d][e5x5][ci], zero-init
    __shared__ float Bt[90];             // bias chunk partials
    __shared__ float Bv[9];              // B[d] = w_r[d].b0
    __shared__ float W5c[459];           // 9 classes x (50 weights + bias)
    __shared__ v2f   swv2[9][6];         // w_sw v-part pairs, 48B/row (16B-aligned)
    __shared__ float exT[2][17][64];     // per-wave TOP-row edge, by parity
    __shared__ float exB[2][17][64];     // per-wave BOTTOM-row edge, by parity
    __shared__ float qsel[10];

    // ---- zero LDS (halos/slot-16 must be 0; Pp must be 0) ----
    for (int i = t; i < 68 * XROW; i += 1024) { xs0[i] = 0.f; xs1[i] = 0.f; }
    for (int i = t; i < 66 * RROW; i += 1024) rs[i] = 0.f;
    for (int i = t; i < 2 * 17 * 64; i += 1024) {
        ((float*)exT)[i] = 0.f; ((float*)exB)[i] = 0.f;
    }
    if (t < 450) Pp[t] = 0.f;
    if (t < 45) {
        int d = t / 5, ap = t - d * 5;
        v2f w; w.x = w_sw[d * 20 + 10 + 2 * ap]; w.y = w_sw[d * 20 + 10 + 2 * ap + 1];
        swv2[d][ap] = w;
    } else if (t >= 64 && t < 73) {
        v2f z; z.x = 0.f; z.y = 0.f;
        swv2[t - 64][5] = z;             // pad lane
    }
    __syncthreads();

    const int row = t >> 4;          // 0..63 (prologue mapping)
    const int cb  = (t & 15) << 2;   // 0,4,...,60

    // ---- stage x (8 contiguous floats = 2x float4 per thread) ----
    {
        const float* xb = x + (size_t)b * 64 * 64 * 2;
        const float4* xp = (const float4*)(xb + (row * 64 + cb) * 2);
        #pragma unroll
        for (int g = 0; g < 2; ++g) {
            float4 v4 = xp[g];
            int px = cb + g * 2;
            xs0[(row + 2) * XROW + px + 2] = v4.x;
            xs1[(row + 2) * XROW + px + 2] = v4.y;
            xs0[(row + 2) * XROW + px + 3] = v4.z;
            xs1[(row + 2) * XROW + px + 3] = v4.w;
        }
    }
    // ---- round A: P chunk partials (1620 items) + bias chunks (90) ----
    for (int idx = t; idx < 1620; idx += 1024) {
        int entry = idx / 10, ch = idx - entry * 10;
        int d = entry / 18, rem = entry % 18;
        int uu = rem >> 1, ci = rem & 1;
        int c0 = ch * 15;
        const float* wr = w_r + d * 150;
        const float* wp = w0 + (uu * 2 + ci) * 150;
        float s = 0.f;
        for (int c = c0; c < c0 + 15; ++c) s += wr[c] * wp[c];
        wtA[idx] = s;
    }
    if (t < 90) {
        int d = t / 10, ch = t - d * 10, c0 = ch * 15;
        float s = 0.f;
        for (int c = c0; c < c0 + 15; ++c) s += w_r[d * 150 + c] * b0[c];
        Bt[t] = s;
    }
    __syncthreads();
    // ---- round B: reduce P entries (162) and B (9) ----
    if (t < 162) {
        float s = 0.f;
        #pragma unroll
        for (int i = 0; i < 10; ++i) s += wtA[t * 10 + i];
        int d = t / 18, rem = t % 18;
        int uu = rem >> 1, ci = rem & 1;
        int dy = d / 3 - 1, dx = d % 3 - 1;
        int uy = uu / 3 - 1, ux = uu % 3 - 1;
        int eidx = (dy + uy + 2) * 5 + (dx + ux + 2);
        Pp[d * 50 + eidx * 2 + ci] = s;
    } else if (t >= 256 && t < 265) {
        int d = t - 256;
        float s = 0.f;
        #pragma unroll
        for (int i = 0; i < 10; ++i) s += Bt[d * 10 + i];
        Bv[d] = s;
    }
    __syncthreads();
    // ---- round C: class subset-sums W5c[9][51] ----
    if (t < 459) {
        int cls = t / 51, j = t - cls * 51;
        int cy = cls / 3, cx = cls % 3;
        float s = 0.f;
        #pragma unroll
        for (int d = 0; d < 9; ++d) {
            int dy = d / 3 - 1, dx = d % 3 - 1;
            bool ok = (cy == 0 || (cy == 1 ? dy >= 0 : dy <= 0)) &&
                      (cx == 0 || (cx == 1 ? dx >= 0 : dx <= 0));
            if (ok) s += (j < 50) ? Pp[d * 50 + j] : Bv[d];
        }
        W5c[t] = s;
    }
    __syncthreads();

    // ---- r everywhere via class-weighted 5x5 stencil (4 px/thread) ----
    {
        int cy = (row == 0) ? 1 : (row == 63) ? 2 : 0;
        #pragma unroll
        for (int p = 0; p < 4; ++p) {
            int xx = cb + p;
            int cx = (xx == 0) ? 1 : (xx == 63) ? 2 : 0;
            const float* Wp = &W5c[(cy * 3 + cx) * 51];
            float acc = Wp[50];
            #pragma unroll
            for (int e = 0; e < 25; ++e) {
                int xi = (row + e / 5) * XROW + (xx + e % 5);
                acc = fmaf(xs0[xi], Wp[e * 2], acc);
                acc = fmaf(xs1[xi], Wp[e * 2 + 1], acc);
            }
            rs[(row + 1) * RROW + xx + 2] = acc;
        }
    }
    __syncthreads();

    // ============ column-per-lane mapping from here on ============
    const int c  = t & 63;           // column 0..63 (lane)
    const int w  = t >> 6;           // wave 0..15, owns rows 4w..4w+3
    const int r0 = w << 2;
    const int upSlot = (w == 0)  ? 16 : w - 1;   // exB[.][upSlot] = row r0-1
    const int dnSlot = (w == 15) ? 16 : w + 1;   // exT[.][dnSlot] = row r0+4
    const int K = VInum[0];

    // ---- Rsw precompute + first step (w_q): r window via DPP ----
    v2f Rsw2[4][5];
    float vprev[4];
    float RC[6], RL[6], RR[6];
    #pragma unroll
    for (int j = 0; j < 6; ++j) RC[j] = rs[(r0 + j) * RROW + c + 2];  // rows r0-1..r0+4
    #pragma unroll
    for (int j = 0; j < 6; ++j) { RL[j] = dppsh<DPP_SHR1>(RC[j]); RR[j] = dppsh<DPP_SHL1>(RC[j]); }
    {
        float vmax[4];
        #pragma unroll
        for (int a = 0; a < 10; ++a) {
            #pragma unroll
            for (int i = 0; i < 4; ++i) {
                float accR = 0.f, accQ = 0.f;
                #pragma unroll
                for (int d = 0; d < 9; ++d) {
                    const int dy = d / 3, dx = d % 3;
                    const float rv = (dx == 0 ? RL : dx == 1 ? RC : RR)[i + dy];
                    accR = fmaf(w_sw[d * 20 + a], rv, accR);
                    accQ = fmaf(w_q[d * 20 + a],  rv, accQ);
                }
                if (a & 1) Rsw2[i][a >> 1].y = accR; else Rsw2[i][a >> 1].x = accR;
                vmax[i] = (a == 0) ? accQ : fmaxf(vmax[i], accQ);
            }
        }
        exT[1][w][c] = vmax[0];          // v^1 edges, parity 1
        exB[1][w][c] = vmax[3];
        #pragma unroll
        for (int i = 0; i < 4; ++i) vprev[i] = vmax[i];
    }
    __syncthreads();

    // ---- K-1 shared-weight VI steps: d-outer, LDS-broadcast weights ----
    for (int k = 2; k <= K; ++k) {
        const int pr = (k - 1) & 1, pw = k & 1;
        float VC[6], VL[6], VR[6];
        VC[0] = exB[pr][upSlot][c];      // row r0-1 (neighbor wave / halo 0)
        VC[5] = exT[pr][dnSlot][c];      // row r0+4
        #pragma unroll
        for (int i = 0; i < 4; ++i) VC[i + 1] = vprev[i];
        #pragma unroll
        for (int j = 0; j < 6; ++j) { VL[j] = dppsh<DPP_SHR1>(VC[j]); VR[j] = dppsh<DPP_SHL1>(VC[j]); }

        v2f acc[4][5];
        #pragma unroll
        for (int d = 0; d < 9; ++d) {
            // 5 weight pairs for this d: 2x ds_read_b128 + 1x ds_read_b64,
            // broadcast (wave-uniform address), in-order lgkmcnt
            const float4* wq = (const float4*)&swv2[d][0];
            float4 wA = wq[0], wB = wq[1];
            v2f w4 = swv2[d][4];
            v2f wd[5];
            wd[0].x = wA.x; wd[0].y = wA.y;
            wd[1].x = wA.z; wd[1].y = wA.w;
            wd[2].x = wB.x; wd[2].y = wB.y;
            wd[3].x = wB.z; wd[3].y = wB.w;
            wd[4] = w4;
            const int dy = d / 3, dx = d % 3;
            const float* S = (dx == 0) ? VL : (dx == 1) ? VC : VR;
            #pragma unroll
            for (int ap = 0; ap < 5; ++ap) {
                #pragma unroll
                for (int i = 0; i < 4; ++i)
                    acc[i][ap] = (d == 0) ? pkfma(wd[ap], S[i + dy], Rsw2[i][ap])
                                          : pkfma(wd[ap], S[i + dy], acc[i][ap]);
            }
        }
        float vnew[4];
        #pragma unroll
        for (int i = 0; i < 4; ++i) {
            v2f m2 = acc[i][0];
            #pragma unroll
            for (int ap = 1; ap < 5; ++ap) m2 = pkmax(m2, acc[i][ap]);
            vnew[i] = fmaxf(m2.x, m2.y);
        }
        exT[pw][w][c] = vnew[0];         // publish v^k edges
        exB[pw][w][c] = vnew[3];
        #pragma unroll
        for (int i = 0; i < 4; ++i) vprev[i] = vnew[i];
        __syncthreads();
    }

    // ---- final step with w_sw2: q -> global, gather (S1,S2) ----
    const int s1 = S1[b], s2 = S2[b];
    {
        const int pK = K & 1;
        float VC[6], VL[6], VR[6];
        VC[0] = exB[pK][upSlot][c];
        VC[5] = exT[pK][dnSlot][c];
        #pragma unroll
        for (int i = 0; i < 4; ++i) VC[i + 1] = vprev[i];
        #pragma unroll
        for (int j = 0; j < 6; ++j) { VL[j] = dppsh<DPP_SHR1>(VC[j]); VR[j] = dppsh<DPP_SHL1>(VC[j]); }

        float qv[4][10];
        #pragma unroll
        for (int a = 0; a < 10; ++a) {
            #pragma unroll
            for (int i = 0; i < 4; ++i) {
                float acc = 0.f;
                #pragma unroll
                for (int d = 0; d < 9; ++d) {
                    const int dy = d / 3, dx = d % 3;
                    acc = fmaf(w_sw2[d * 20 + a],
                               (dx == 0 ? RL : dx == 1 ? RC : RR)[i + dy], acc);
                    acc = fmaf(w_sw2[d * 20 + 10 + a],
                               (dx == 0 ? VL : dx == 1 ? VC : VR)[i + dy], acc);
                }
                qv[i][a] = acc;
            }
        }
        // store q: 10 floats per px, 8B-aligned -> 5x float2 per row
        #pragma unroll
        for (int i = 0; i < 4; ++i) {
            float2* qp = (float2*)(out + 2048 +
                          ((size_t)((b * 64 + r0 + i) * 64 + c)) * 10);
            #pragma unroll
            for (int g = 0; g < 5; ++g)
                qp[g] = make_float2(qv[i][2 * g], qv[i][2 * g + 1]);
        }
        if (c == s2) {
            #pragma unroll
            for (int i = 0; i < 4; ++i)
                if (s1 == r0 + i) {
                    #pragma unroll
                    for (int a = 0; a < 10; ++a) qsel[a] = qv[i][a];
                }
        }
    }
    __syncthreads();

    // ---- dense + softmax (thread 0), q_out (threads 0..9) ----
    if (t == 0) {
        float logits[8];
        float m = -1e30f;
        #pragma unroll
        for (int j = 0; j < 8; ++j) {
            float s = 0.f;
            #pragma unroll
            for (int a = 0; a < 10; ++a) s += qsel[a] * w_dense[a * 8 + j];
            logits[j] = s;
            m = fmaxf(m, s);
        }
        float sum = 0.f;
        float e[8];
        #pragma unroll
        for (int j = 0; j < 8; ++j) { e[j] = expf(logits[j] - m); sum += e[j]; }
        float inv = 1.f / sum;
        #pragma unroll
        for (int j = 0; j < 8; ++j) {
            out[b * 8 + j] = logits[j];
            out[1024 + b * 8 + j] = e[j] * inv;
        }
    }
    if (t < 10) out[5244928 + b * 10 + t] = qsel[t];
}

extern "C" void kernel_launch(void* const* d_in, const int* in_sizes, int n_in,
                              void* d_out, int out_size, void* d_ws, size_t ws_size,
                              hipStream_t stream) {
    const float* x      = (const float*)d_in[0];
    const int*   S1     = (const int*)d_in[1];
    const int*   S2     = (const int*)d_in[2];
    const int*   VInum  = (const int*)d_in[3];
    const float* w0     = (const float*)d_in[4];
    const float* b0     = (const float*)d_in[5];
    const float* w_r    = (const float*)d_in[6];
    const float* w_q    = (const float*)d_in[7];
    const float* w_sw   = (const float*)d_in[8];
    const float* w_sw2  = (const float*)d_in[9];
    const float* w_dense= (const float*)d_in[10];
    float* out = (float*)d_out;

    vin_kernel<<<128, 1024, 0, stream>>>(x, S1, S2, VInum, w0, b0, w_r, w_q,
                                         w_sw, w_sw2, w_dense, out);
}

// Round 14
// 183.013 us; speedup vs baseline: 1.7048x; 1.2550x over previous
//
#include <hip/hip_runtime.h>
#include <math.h>

// VIN forward on MI355X — single fused kernel, 128 WGs x 1024 thr (16 waves).
// Sizes: N=128, H=W=64, CH_I=2, CH_H=150, CH_Q=10, N_ACT=8, VInum=36.
//
// R23 -> R24 (temporal blocking x2 on the R19-best structure):
//  Operand-path campaign closed: s_load weights (102us) beat VMEM (246),
//  LDS-broadcast (164), and register residency (impossible/capped). R19
//  accounting: VALU issues ~0.8us of each 2.3us iter -> all 4 waves/SIMD
//  stalled ~1.5us/iter together; only the per-iter barrier convoy or shared
//  SQC can do that. Attack the barrier term: 2 VI steps per barrier.
//  DPP layout makes it cheap: horizontal halo is free (full 64 cols in the
//  wave), vertical needs 2-row ghosts. Per block: read float2 ghosts from
//  both neighbors (2x ds_read_b64), step A on rows r0-1..r0+4 (6 rows, +25%
//  redundant FMA), step B on rows r0..r0+3 from registers, publish 4 rows
//  (2x ds_write_b64), ONE barrier. Barriers 35 -> ~19; DS ops halved.
//  Ghost rows computed with the identical formula/order as the neighbor's
//  copy -> bit-identical; out-of-image ghosts forced to 0 (= SAME padding).
//  Rsw2 extends to 6 rows (prologue, from rs). ap-pass split {2,2,1} with
//  per-pass DPP recompute keeps peak VGPR ~<=128.
//  Pre-committed: null (99-105us) -> barrier innocent, near structural floor.

typedef float v2f __attribute__((ext_vector_type(2)));

static __device__ __forceinline__ v2f splat2(float s) { v2f r; r.x = s; r.y = s; return r; }
static __device__ __forceinline__ v2f pkfma(v2f w, float v, v2f a) {
#if __has_builtin(__builtin_elementwise_fma)
    return __builtin_elementwise_fma(w, splat2(v), a);
#else
    v2f r; r.x = fmaf(w.x, v, a.x); r.y = fmaf(w.y, v, a.y); return r;
#endif
}
static __device__ __forceinline__ v2f pkmax(v2f a, v2f b) {
#if __has_builtin(__builtin_elementwise_max)
    return __builtin_elementwise_max(a, b);
#else
    v2f r; r.x = fmaxf(a.x, b.x); r.y = fmaxf(a.y, b.y); return r;
#endif
}

// DPP wave-wide shift by one lane. bound-invalid lanes keep old (=0) ->
// zero halo at lanes 0/63.
#define DPP_SHR1 0x138   // lane n <- lane n-1  (left-neighbor value)
#define DPP_SHL1 0x130   // lane n <- lane n+1  (right-neighbor value)
template <int CTRL>
static __device__ __forceinline__ float dppsh(float v) {
    return __int_as_float(__builtin_amdgcn_update_dpp(
        0, __float_as_int(v), CTRL, 0xF, 0xF, false));
}

#define XROW 69
#define RROW 68                  // rs row stride; idx = (grow+1)*68 + col + 2

__global__ void
__attribute__((amdgpu_flat_work_group_size(1024, 1024)))
__attribute__((amdgpu_waves_per_eu(4, 4)))
vin_kernel(const float* __restrict__ x,
           const int* __restrict__ S1,
           const int* __restrict__ S2,
           const int* __restrict__ VInum,
           const float* __restrict__ w0,
           const float* __restrict__ b0,
           const float* __restrict__ w_r,
           const float* __restrict__ w_q,
           const float* __restrict__ w_sw,
           const float* __restrict__ w_sw2,
           const float* __restrict__ w_dense,
           float* __restrict__ out) {
    const int b = blockIdx.x;
    const int t = threadIdx.x;

    __shared__ float  xs0[68 * XROW];    // x ch0, [y+2][x+2], 2-halo of zeros
    __shared__ float  xs1[68 * XROW];    // x ch1
    __shared__ float  rs[66 * RROW];     // r, pad-2 layout, zero halos
    __shared__ float  wtA[1620];         // P chunk partials: 162 entries x 10
    __shared__ float  Pp[450];           // P[d][e5x5][ci], zero-init
    __shared__ float  Bt[90];            // bias chunk partials
    __shared__ float  Bv[9];             // B[d] = w_r[d].b0
    __shared__ float  W5c[459];          // 9 classes x (50 weights + bias)
    __shared__ float2 exU[2][17][64];    // wave rows (r0, r0+1), by parity
    __shared__ float2 exD[2][17][64];    // wave rows (r0+2, r0+3), by parity
    __shared__ float  qsel[10];

    // ---- zero LDS (halos/slot-16 must be 0; Pp must be 0) ----
    for (int i = t; i < 68 * XROW; i += 1024) { xs0[i] = 0.f; xs1[i] = 0.f; }
    for (int i = t; i < 66 * RROW; i += 1024) rs[i] = 0.f;
    for (int i = t; i < 2 * 17 * 64; i += 1024) {
        ((float2*)exU)[i] = make_float2(0.f, 0.f);
        ((float2*)exD)[i] = make_float2(0.f, 0.f);
    }
    if (t < 450) Pp[t] = 0.f;
    __syncthreads();

    const int row = t >> 4;          // 0..63 (prologue mapping)
    const int cb  = (t & 15) << 2;   // 0,4,...,60

    // ---- stage x (8 contiguous floats = 2x float4 per thread) ----
    {
        const float* xb = x + (size_t)b * 64 * 64 * 2;
        const float4* xp = (const float4*)(xb + (row * 64 + cb) * 2);
        #pragma unroll
        for (int g = 0; g < 2; ++g) {
            float4 v4 = xp[g];
            int px = cb + g * 2;
            xs0[(row + 2) * XROW + px + 2] = v4.x;
            xs1[(row + 2) * XROW + px + 2] = v4.y;
            xs0[(row + 2) * XROW + px + 3] = v4.z;
            xs1[(row + 2) * XROW + px + 3] = v4.w;
        }
    }
    // ---- round A: P chunk partials (1620 items) + bias chunks (90) ----
    for (int idx = t; idx < 1620; idx += 1024) {
        int entry = idx / 10, ch = idx - entry * 10;
        int d = entry / 18, rem = entry % 18;
        int uu = rem >> 1, ci = rem & 1;
        int c0 = ch * 15;
        const float* wr = w_r + d * 150;
        const float* wp = w0 + (uu * 2 + ci) * 150;
        float s = 0.f;
        for (int c = c0; c < c0 + 15; ++c) s += wr[c] * wp[c];
        wtA[idx] = s;
    }
    if (t < 90) {
        int d = t / 10, ch = t - d * 10, c0 = ch * 15;
        float s = 0.f;
        for (int c = c0; c < c0 + 15; ++c) s += w_r[d * 150 + c] * b0[c];
        Bt[t] = s;
    }
    __syncthreads();
    // ---- round B: reduce P entries (162) and B (9) ----
    if (t < 162) {
        float s = 0.f;
        #pragma unroll
        for (int i = 0; i < 10; ++i) s += wtA[t * 10 + i];
        int d = t / 18, rem = t % 18;
        int uu = rem >> 1, ci = rem & 1;
        int dy = d / 3 - 1, dx = d % 3 - 1;
        int uy = uu / 3 - 1, ux = uu % 3 - 1;
        int eidx = (dy + uy + 2) * 5 + (dx + ux + 2);
        Pp[d * 50 + eidx * 2 + ci] = s;
    } else if (t >= 256 && t < 265) {
        int d = t - 256;
        float s = 0.f;
        #pragma unroll
        for (int i = 0; i < 10; ++i) s += Bt[d * 10 + i];
        Bv[d] = s;
    }
    __syncthreads();
    // ---- round C: class subset-sums W5c[9][51] ----
    if (t < 459) {
        int cls = t / 51, j = t - cls * 51;
        int cy = cls / 3, cx = cls % 3;
        float s = 0.f;
        #pragma unroll
        for (int d = 0; d < 9; ++d) {
            int dy = d / 3 - 1, dx = d % 3 - 1;
            bool ok = (cy == 0 || (cy == 1 ? dy >= 0 : dy <= 0)) &&
                      (cx == 0 || (cx == 1 ? dx >= 0 : dx <= 0));
            if (ok) s += (j < 50) ? Pp[d * 50 + j] : Bv[d];
        }
        W5c[t] = s;
    }
    __syncthreads();

    // ---- r everywhere via class-weighted 5x5 stencil (4 px/thread) ----
    {
        int cy = (row == 0) ? 1 : (row == 63) ? 2 : 0;
        #pragma unroll
        for (int p = 0; p < 4; ++p) {
            int xx = cb + p;
            int cx = (xx == 0) ? 1 : (xx == 63) ? 2 : 0;
            const float* Wp = &W5c[(cy * 3 + cx) * 51];
            float acc = Wp[50];
            #pragma unroll
            for (int e = 0; e < 25; ++e) {
                int xi = (row + e / 5) * XROW + (xx + e % 5);
                acc = fmaf(xs0[xi], Wp[e * 2], acc);
                acc = fmaf(xs1[xi], Wp[e * 2 + 1], acc);
            }
            rs[(row + 1) * RROW + xx + 2] = acc;
        }
    }
    __syncthreads();

    // ============ column-per-lane mapping from here on ============
    const int c  = t & 63;           // column 0..63 (lane)
    const int w  = t >> 6;           // wave 0..15, owns rows 4w..4w+3
    const int r0 = w << 2;
    const int upSlot = (w == 0)  ? 16 : w - 1;
    const int dnSlot = (w == 15) ? 16 : w + 1;
    const int K = VInum[0];

    // ---- prologue: Rsw2 for 6 rows (r0-1..r0+4) + v^1 (own 4 rows) ----
    v2f Rsw2[6][5];                  // Rsw2[i] is for row r0-1+i
    float vprev[4];
    {
        float RC2[8], RL2[8], RR2[8];
        #pragma unroll
        for (int j = 0; j < 8; ++j) {
            int grow = r0 - 2 + j;                       // r0-2 .. r0+5
            int gcl = grow < -1 ? -1 : (grow > 64 ? 64 : grow);  // clamp into rs
            RC2[j] = rs[(gcl + 1) * RROW + c + 2];
        }
        #pragma unroll
        for (int j = 0; j < 8; ++j) {
            RL2[j] = dppsh<DPP_SHR1>(RC2[j]); RR2[j] = dppsh<DPP_SHL1>(RC2[j]);
        }
        float vmax[4];
        #pragma unroll
        for (int a = 0; a < 10; ++a) {
            #pragma unroll
            for (int i = 0; i < 6; ++i) {                // Rsw rows r0-1..r0+4
                float accR = 0.f;
                #pragma unroll
                for (int d = 0; d < 9; ++d) {
                    const int dy = d / 3, dx = d % 3;
                    const float rv = (dx == 0 ? RL2 : dx == 1 ? RC2 : RR2)[i + dy];
                    accR = fmaf(w_sw[d * 20 + a], rv, accR);
                }
                if (a & 1) Rsw2[i][a >> 1].y = accR; else Rsw2[i][a >> 1].x = accR;
            }
            #pragma unroll
            for (int j = 0; j < 4; ++j) {                // v^1 own rows r0..r0+3
                float accQ = 0.f;
                #pragma unroll
                for (int d = 0; d < 9; ++d) {
                    const int dy = d / 3, dx = d % 3;
                    const float rv = (dx == 0 ? RL2 : dx == 1 ? RC2 : RR2)[j + 1 + dy];
                    accQ = fmaf(w_q[d * 20 + a], rv, accQ);
                }
                vmax[j] = (a == 0) ? accQ : fmaxf(vmax[j], accQ);
            }
        }
        exU[0][w][c] = make_float2(vmax[0], vmax[1]);
        exD[0][w][c] = make_float2(vmax[2], vmax[3]);
        #pragma unroll
        for (int j = 0; j < 4; ++j) vprev[j] = vmax[j];
    }

    // ---- K-loop: blocks of 2 VI steps per barrier ----
    int cur = 0;
    int k = 2;
    for (; k + 1 <= K; k += 2) {
        __syncthreads();                 // prev publishes visible; reads done
        float2 gU = exD[cur][upSlot][c]; // v^{k-1} rows r0-2, r0-1
        float2 gD = exU[cur][dnSlot][c]; // v^{k-1} rows r0+4, r0+5
        float VC[8];
        VC[0] = gU.x; VC[1] = gU.y;
        #pragma unroll
        for (int j = 0; j < 4; ++j) VC[2 + j] = vprev[j];
        VC[6] = gD.x; VC[7] = gD.y;

        // ---- step A: v^k at rows r0-1..r0+4 (vA[0..5]) ----
        float vA[6];
        v2f vmA[6];
        // pass ap = 0,1
        {
            float VL[8], VR[8];
            #pragma unroll
            for (int j = 0; j < 8; ++j) { VL[j] = dppsh<DPP_SHR1>(VC[j]); VR[j] = dppsh<DPP_SHL1>(VC[j]); }
            v2f acc[6][2];
            #pragma unroll
            for (int ap = 0; ap < 2; ++ap)
                #pragma unroll
                for (int d = 0; d < 9; ++d) {
                    v2f w2; w2.x = w_sw[d * 20 + 10 + 2 * ap]; w2.y = w_sw[d * 20 + 10 + 2 * ap + 1];
                    const int dy = d / 3, dx = d % 3;
                    const float* S = (dx == 0) ? VL : (dx == 1) ? VC : VR;
                    #pragma unroll
                    for (int i = 0; i < 6; ++i)
                        acc[i][ap] = (d == 0) ? pkfma(w2, S[i + dy], Rsw2[i][ap])
                                              : pkfma(w2, S[i + dy], acc[i][ap]);
                }
            #pragma unroll
            for (int i = 0; i < 6; ++i) vmA[i] = pkmax(acc[i][0], acc[i][1]);
        }
        // pass ap = 2,3
        {
            float VL[8], VR[8];
            #pragma unroll
            for (int j = 0; j < 8; ++j) { VL[j] = dppsh<DPP_SHR1>(VC[j]); VR[j] = dppsh<DPP_SHL1>(VC[j]); }
            v2f acc[6][2];
            #pragma unroll
            for (int ap = 0; ap < 2; ++ap)
                #pragma unroll
                for (int d = 0; d < 9; ++d) {
                    const int apx = 2 + ap;
                    v2f w2; w2.x = w_sw[d * 20 + 10 + 2 * apx]; w2.y = w_sw[d * 20 + 10 + 2 * apx + 1];
                    const int dy = d / 3, dx = d % 3;
                    const float* S = (dx == 0) ? VL : (dx == 1) ? VC : VR;
                    #pragma unroll
                    for (int i = 0; i < 6; ++i)
                        acc[i][ap] = (d == 0) ? pkfma(w2, S[i + dy], Rsw2[i][apx])
                                              : pkfma(w2, S[i + dy], acc[i][ap]);
                }
            #pragma unroll
            for (int i = 0; i < 6; ++i) vmA[i] = pkmax(pkmax(vmA[i], acc[i][0]), acc[i][1]);
        }
        // pass ap = 4
        {
            float VL[8], VR[8];
            #pragma unroll
            for (int j = 0; j < 8; ++j) { VL[j] = dppsh<DPP_SHR1>(VC[j]); VR[j] = dppsh<DPP_SHL1>(VC[j]); }
            v2f acc[6];
            #pragma unroll
            for (int d = 0; d < 9; ++d) {
                v2f w2; w2.x = w_sw[d * 20 + 10 + 8]; w2.y = w_sw[d * 20 + 10 + 9];
                const int dy = d / 3, dx = d % 3;
                const float* S = (dx == 0) ? VL : (dx == 1) ? VC : VR;
                #pragma unroll
                for (int i = 0; i < 6; ++i)
                    acc[i] = (d == 0) ? pkfma(w2, S[i + dy], Rsw2[i][4])
                                      : pkfma(w2, S[i + dy], acc[i]);
            }
            #pragma unroll
            for (int i = 0; i < 6; ++i) vmA[i] = pkmax(vmA[i], acc[i]);
        }
        #pragma unroll
        for (int i = 0; i < 6; ++i) vA[i] = fmaxf(vmA[i].x, vmA[i].y);
        if (w == 0)  vA[0] = 0.f;        // row -1 is image padding
        if (w == 15) vA[5] = 0.f;        // row 64 is image padding

        // ---- step B: v^{k+1} at rows r0..r0+3 from vA (all registers) ----
        float vB[4];
        v2f vmB[4];
        {
            float VL[6], VR[6];
            #pragma unroll
            for (int j = 0; j < 6; ++j) { VL[j] = dppsh<DPP_SHR1>(vA[j]); VR[j] = dppsh<DPP_SHL1>(vA[j]); }
            v2f acc[4][2];
            #pragma unroll
            for (int ap = 0; ap < 2; ++ap)
                #pragma unroll
                for (int d = 0; d < 9; ++d) {
                    v2f w2; w2.x = w_sw[d * 20 + 10 + 2 * ap]; w2.y = w_sw[d * 20 + 10 + 2 * ap + 1];
                    const int dy = d / 3, dx = d % 3;
                    const float* S = (dx == 0) ? VL : (dx == 1) ? vA : VR;
                    #pragma unroll
                    for (int j = 0; j < 4; ++j)
                        acc[j][ap] = (d == 0) ? pkfma(w2, S[j + dy], Rsw2[j + 1][ap])
                                              : pkfma(w2, S[j + dy], acc[j][ap]);
                }
            #pragma unroll
            for (int j = 0; j < 4; ++j) vmB[j] = pkmax(acc[j][0], acc[j][1]);
        }
        {
            float VL[6], VR[6];
            #pragma unroll
            for (int j = 0; j < 6; ++j) { VL[j] = dppsh<DPP_SHR1>(vA[j]); VR[j] = dppsh<DPP_SHL1>(vA[j]); }
            v2f acc[4][2];
            #pragma unroll
            for (int ap = 0; ap < 2; ++ap)
                #pragma unroll
                for (int d = 0; d < 9; ++d) {
                    const int apx = 2 + ap;
                    v2f w2; w2.x = w_sw[d * 20 + 10 + 2 * apx]; w2.y = w_sw[d * 20 + 10 + 2 * apx + 1];
                    const int dy = d / 3, dx = d % 3;
                    const float* S = (dx == 0) ? VL : (dx == 1) ? vA : VR;
                    #pragma unroll
                    for (int j = 0; j < 4; ++j)
                        acc[j][ap] = (d == 0) ? pkfma(w2, S[j + dy], Rsw2[j + 1][apx])
                                              : pkfma(w2, S[j + dy], acc[j][ap]);
                }
            #pragma unroll
            for (int j = 0; j < 4; ++j) vmB[j] = pkmax(pkmax(vmB[j], acc[j][0]), acc[j][1]);
        }
        {
            float VL[6], VR[6];
            #pragma unroll
            for (int j = 0; j < 6; ++j) { VL[j] = dppsh<DPP_SHR1>(vA[j]); VR[j] = dppsh<DPP_SHL1>(vA[j]); }
            v2f acc[4];
            #pragma unroll
            for (int d = 0; d < 9; ++d) {
                v2f w2; w2.x = w_sw[d * 20 + 10 + 8]; w2.y = w_sw[d * 20 + 10 + 9];
                const int dy = d / 3, dx = d % 3;
                const float* S = (dx == 0) ? VL : (dx == 1) ? vA : VR;
                #pragma unroll
                for (int j = 0; j < 4; ++j)
                    acc[j] = (d == 0) ? pkfma(w2, S[j + dy], Rsw2[j + 1][4])
                                      : pkfma(w2, S[j + dy], acc[j]);
            }
            #pragma unroll
            for (int j = 0; j < 4; ++j) vmB[j] = pkmax(vmB[j], acc[j]);
        }
        #pragma unroll
        for (int j = 0; j < 4; ++j) vB[j] = fmaxf(vmB[j].x, vmB[j].y);

        // ---- publish v^{k+1}, carry ----
        int nxt = cur ^ 1;
        exU[nxt][w][c] = make_float2(vB[0], vB[1]);
        exD[nxt][w][c] = make_float2(vB[2], vB[3]);
        #pragma unroll
        for (int j = 0; j < 4; ++j) vprev[j] = vB[j];
        cur = nxt;
    }

    // ---- tail: one remaining VI step (K-1 odd) ----
    if (k <= K) {
        __syncthreads();
        float gu = exD[cur][upSlot][c].y;    // row r0-1
        float gd = exU[cur][dnSlot][c].x;    // row r0+4
        float VC1[6];
        VC1[0] = gu;
        #pragma unroll
        for (int j = 0; j < 4; ++j) VC1[1 + j] = vprev[j];
        VC1[5] = gd;
        float VL1[6], VR1[6];
        #pragma unroll
        for (int j = 0; j < 6; ++j) { VL1[j] = dppsh<DPP_SHR1>(VC1[j]); VR1[j] = dppsh<DPP_SHL1>(VC1[j]); }
        v2f acc[4][5];
        #pragma unroll
        for (int ap = 0; ap < 5; ++ap)
            #pragma unroll
            for (int d = 0; d < 9; ++d) {
                v2f w2; w2.x = w_sw[d * 20 + 10 + 2 * ap]; w2.y = w_sw[d * 20 + 10 + 2 * ap + 1];
                const int dy = d / 3, dx = d % 3;
                const float* S = (dx == 0) ? VL1 : (dx == 1) ? VC1 : VR1;
                #pragma unroll
                for (int j = 0; j < 4; ++j)
                    acc[j][ap] = (d == 0) ? pkfma(w2, S[j + dy], Rsw2[j + 1][ap])
                                          : pkfma(w2, S[j + dy], acc[j][ap]);
            }
        float vB[4];
        #pragma unroll
        for (int j = 0; j < 4; ++j) {
            v2f m2 = acc[j][0];
            #pragma unroll
            for (int ap = 1; ap < 5; ++ap) m2 = pkmax(m2, acc[j][ap]);
            vB[j] = fmaxf(m2.x, m2.y);
        }
        int nxt = cur ^ 1;
        exU[nxt][w][c] = make_float2(vB[0], vB[1]);
        exD[nxt][w][c] = make_float2(vB[2], vB[3]);
        #pragma unroll
        for (int j = 0; j < 4; ++j) vprev[j] = vB[j];
        cur = nxt;
    }

    // ---- final step with w_sw2: q -> global, gather (S1,S2) ----
    __syncthreads();
    const int s1 = S1[b], s2 = S2[b];
    {
        float gu = exD[cur][upSlot][c].y;    // v^K row r0-1
        float gd = exU[cur][dnSlot][c].x;    // v^K row r0+4
        float VCf[6], VLf[6], VRf[6], RCf[6], RLf[6], RRf[6];
        VCf[0] = gu;
        #pragma unroll
        for (int j = 0; j < 4; ++j) VCf[1 + j] = vprev[j];
        VCf[5] = gd;
        #pragma unroll
        for (int j = 0; j < 6; ++j) RCf[j] = rs[(r0 + j) * RROW + c + 2];  // rows r0-1..r0+4
        #pragma unroll
        for (int j = 0; j < 6; ++j) {
            VLf[j] = dppsh<DPP_SHR1>(VCf[j]); VRf[j] = dppsh<DPP_SHL1>(VCf[j]);
            RLf[j] = dppsh<DPP_SHR1>(RCf[j]); RRf[j] = dppsh<DPP_SHL1>(RCf[j]);
        }
        float qv[4][10];
        #pragma unroll
        for (int a = 0; a < 10; ++a) {
            #pragma unroll
            for (int i = 0; i < 4; ++i) {
                float acc = 0.f;
                #pragma unroll
                for (int d = 0; d < 9; ++d) {
                    const int dy = d / 3, dx = d % 3;
                    acc = fmaf(w_sw2[d * 20 + a],
                               (dx == 0 ? RLf : dx == 1 ? RCf : RRf)[i + dy], acc);
                    acc = fmaf(w_sw2[d * 20 + 10 + a],
                               (dx == 0 ? VLf : dx == 1 ? VCf : VRf)[i + dy], acc);
                }
                qv[i][a] = acc;
            }
        }
        // store q: 10 floats per px, 8B-aligned -> 5x float2 per row
        #pragma unroll
        for (int i = 0; i < 4; ++i) {
            float2* qp = (float2*)(out + 2048 +
                          ((size_t)((b * 64 + r0 + i) * 64 + c)) * 10);
            #pragma unroll
            for (int g = 0; g < 5; ++g)
                qp[g] = make_float2(qv[i][2 * g], qv[i][2 * g + 1]);
        }
        if (c == s2) {
            #pragma unroll
            for (int i = 0; i < 4; ++i)
                if (s1 == r0 + i) {
                    #pragma unroll
                    for (int a = 0; a < 10; ++a) qsel[a] = qv[i][a];
                }
        }
    }
    __syncthreads();

    // ---- dense + softmax (thread 0), q_out (threads 0..9) ----
    if (t == 0) {
        float logits[8];
        float m = -1e30f;
        #pragma unroll
        for (int j = 0; j < 8; ++j) {
            float s = 0.f;
            #pragma unroll
            for (int a = 0; a < 10; ++a) s += qsel[a] * w_dense[a * 8 + j];
            logits[j] = s;
            m = fmaxf(m, s);
        }
        float sum = 0.f;
        float e[8];
        #pragma unroll
        for (int j = 0; j < 8; ++j) { e[j] = expf(logits[j] - m); sum += e[j]; }
        float inv = 1.f / sum;
        #pragma unroll
        for (int j = 0; j < 8; ++j) {
            out[b * 8 + j] = logits[j];
            out[1024 + b * 8 + j] = e[j] * inv;
        }
    }
    if (t < 10) out[5244928 + b * 10 + t] = qsel[t];
}

extern "C" void kernel_launch(void* const* d_in, const int* in_sizes, int n_in,
                              void* d_out, int out_size, void* d_ws, size_t ws_size,
                              hipStream_t stream) {
    const float* x      = (const float*)d_in[0];
    const int*   S1     = (const int*)d_in[1];
    const int*   S2     = (const int*)d_in[2];
    const int*   VInum  = (const int*)d_in[3];
    const float* w0     = (const float*)d_in[4];
    const float* b0     = (const float*)d_in[5];
    const float* w_r    = (const float*)d_in[6];
    const float* w_q    = (const float*)d_in[7];
    const float* w_sw   = (const float*)d_in[8];
    const float* w_sw2  = (const float*)d_in[9];
    const float* w_dense= (const float*)d_in[10];
    float* out = (float*)d_out;

    vin_kernel<<<128, 1024, 0, stream>>>(x, S1, S2, VInum, w0, b0, w_r, w_q,
                                         w_sw, w_sw2, w_dense, out);
}